// Round 1
// baseline (380.907 us; speedup 1.0000x reference)
//
#include <hip/hip_runtime.h>
#include <hip/hip_bf16.h>
#include <hip/hip_fp16.h>

#define BB 16
#define LL 2048
#define DD 128
#define SCALE 0.08838834764831845f
// LDS: P [32][2048] f16/bf16 = 131072 | mbuf [16][32] f32 = 2048 | maxr[32] f32 = 128
#define LDS_BYTES (131072 + 2048 + 128)

using short8 = __attribute__((ext_vector_type(8))) short;
using f32x4  = __attribute__((ext_vector_type(4))) float;

#define MFMA(a,b,c) __builtin_amdgcn_mfma_f32_16x16x32_bf16((a),(b),(c),0,0,0)

__device__ __forceinline__ unsigned short f2bf(float x){
  unsigned int u = __float_as_uint(x);
  u += 0x7FFFu + ((u >> 16) & 1u);          // RNE to bf16
  return (unsigned short)(u >> 16);
}
__device__ __forceinline__ float bf2f(unsigned short h){
  return __uint_as_float(((unsigned int)h) << 16);
}
__device__ __forceinline__ unsigned int pkh2(float a, float b){
  unsigned int ua = (unsigned int)__half_as_ushort(__float2half_rn(a));
  unsigned int ub = (unsigned int)__half_as_ushort(__float2half_rn(b));
  return ua | (ub << 16);
}
__device__ __forceinline__ float h2f(unsigned short u){
  return __half2float(__ushort_as_half(u));
}
__device__ __forceinline__ short8 pack8(float4 a, float4 b){
  short8 r;
  r[0]=(short)f2bf(a.x); r[1]=(short)f2bf(a.y); r[2]=(short)f2bf(a.z); r[3]=(short)f2bf(a.w);
  r[4]=(short)f2bf(b.x); r[5]=(short)f2bf(b.y); r[6]=(short)f2bf(b.z); r[7]=(short)f2bf(b.w);
  return r;
}

// ---------- pre-kernel 1: K -> bf16 hi/lo split (same [b][k][d] layout) ----------
__global__ __launch_bounds__(256) void prep_k(const float* __restrict__ K,
                                              unsigned short* __restrict__ kh,
                                              unsigned short* __restrict__ kl){
  const size_t i = ((size_t)blockIdx.x * 256 + threadIdx.x) * 8;
  float4 a = *(const float4*)(K + i);
  float4 c = *(const float4*)(K + i + 4);
  float v[8] = {a.x,a.y,a.z,a.w,c.x,c.y,c.z,c.w};
  uint4 hv, lv;
  unsigned int H[4], L[4];
#pragma unroll
  for (int j = 0; j < 4; ++j) {
    unsigned short h0 = f2bf(v[2*j]),   h1 = f2bf(v[2*j+1]);
    unsigned short l0 = f2bf(v[2*j]   - bf2f(h0));
    unsigned short l1 = f2bf(v[2*j+1] - bf2f(h1));
    H[j] = (unsigned int)h0 | ((unsigned int)h1 << 16);
    L[j] = (unsigned int)l0 | ((unsigned int)l1 << 16);
  }
  hv.x=H[0]; hv.y=H[1]; hv.z=H[2]; hv.w=H[3];
  lv.x=L[0]; lv.y=L[1]; lv.z=L[2]; lv.w=L[3];
  *(uint4*)(kh + i) = hv;
  *(uint4*)(kl + i) = lv;
}

// ---------- pre-kernel 2: V [b][k][d] f32 -> Vt [b][d][k] bf16 ----------
__global__ __launch_bounds__(256) void prep_vt(const float* __restrict__ V,
                                               unsigned short* __restrict__ vt){
  __shared__ float t[32][33];
  const int bid = blockIdx.x;
  const int b   = bid >> 8;          // 256 tiles per batch: 64 k-tiles x 4 d-tiles
  const int tt  = bid & 255;
  const int k0  = (tt >> 2) * 32, d0 = (tt & 3) * 32;
  const int tid = threadIdx.x;
  const int r   = tid >> 3, cc = (tid & 7) * 4;
  float4 x = *(const float4*)(V + ((size_t)b*LL + k0 + r)*DD + d0 + cc);
  t[cc+0][r] = x.x; t[cc+1][r] = x.y; t[cc+2][r] = x.z; t[cc+3][r] = x.w;
  __syncthreads();
  float y0 = t[r][cc], y1 = t[r][cc+1], y2 = t[r][cc+2], y3 = t[r][cc+3];
  uint2 o;
  o.x = (unsigned int)f2bf(y0) | ((unsigned int)f2bf(y1) << 16);
  o.y = (unsigned int)f2bf(y2) | ((unsigned int)f2bf(y3) << 16);
  *(uint2*)(vt + ((size_t)b*DD + d0 + r)*LL + k0 + cc) = o;
}

// ---------- main fused kernel: 1 WG = (batch, 32 q-rows), 16 waves ----------
__global__ __launch_bounds__(1024) void attn_main(
    const float* __restrict__ Q, const int* __restrict__ M,
    const unsigned short* __restrict__ Kh, const unsigned short* __restrict__ Kl,
    const unsigned short* __restrict__ Vt,
    float* __restrict__ ctxout, float* __restrict__ pout)
{
  extern __shared__ char lds[];                    // P rows: row*4096 + ((2k)^((row&7)<<4))
  float* mbuf = (float*)(lds + 131072);            // [16][32]
  float* maxr = (float*)(lds + 131072 + 2048);     // [32]

  const int tid = threadIdx.x;
  const int w = tid >> 6;        // wave 0..15
  const int l = tid & 63;
  const int c = l & 15;          // lane col within 16
  const int g = l >> 4;          // lane group 0..3

  // XCD-aware swizzle: 1024 WGs, 8 XCDs, 2 batches per XCD
  const int bid = blockIdx.x;
  const int xcd = bid & 7, ii = bid >> 3;          // ii 0..127
  const int b  = xcd*2 + (ii >> 6);
  const int q0 = (ii & 63) * 32;

  // ---- Q fragments (B-operand of S^T = K * Q^T): bf16, [qtile][dchunk]
  short8 qf[2][4];
#pragma unroll
  for (int qtl = 0; qtl < 2; ++qtl)
#pragma unroll
    for (int dc = 0; dc < 4; ++dc) {
      const float* qp = Q + ((size_t)b*LL + q0 + qtl*16 + c)*DD + dc*32 + g*8;
      float4 u0 = *(const float4*)qp;
      float4 u1 = *(const float4*)(qp + 4);
      qf[qtl][dc] = pack8(u0, u1);
    }

  // ---- Phase A: S^T tiles via MFMA, mask+scale, f16 -> LDS, running row-max
  float rmax0 = -3.0e38f, rmax1 = -3.0e38f;
  const int kcw = w * 128;                         // this wave's k-chunk
#pragma unroll 1
  for (int kt = 0; kt < 8; ++kt) {
    const int krow = kcw + kt*16 + c;
    const unsigned short* khp = Kh + ((size_t)b*LL + krow)*DD + g*8;
    const unsigned short* klp = Kl + ((size_t)b*LL + krow)*DD + g*8;
    short8 ah[4], al[4];
#pragma unroll
    for (int dc = 0; dc < 4; ++dc) {
      ah[dc] = *(const short8*)(khp + dc*32);
      al[dc] = *(const short8*)(klp + dc*32);
    }
#pragma unroll
    for (int qtl = 0; qtl < 2; ++qtl) {
      f32x4 acc = {0.f,0.f,0.f,0.f};
#pragma unroll
      for (int dc = 0; dc < 4; ++dc) acc = MFMA(ah[dc], qf[qtl][dc], acc);
#pragma unroll
      for (int dc = 0; dc < 4; ++dc) acc = MFMA(al[dc], qf[qtl][dc], acc);
      const int qg = q0 + qtl*16 + c;              // global q (C col)
      const int kb = kcw + kt*16 + g*4;            // k of acc[0] (C rows are 4 consecutive k)
      const int4 mv = *(const int4*)(M + ((size_t)b*LL + qg)*LL + kb);
      float s0 = mv.x ? acc[0]*SCALE : -1e9f;
      float s1 = mv.y ? acc[1]*SCALE : -1e9f;
      float s2 = mv.z ? acc[2]*SCALE : -1e9f;
      float s3 = mv.w ? acc[3]*SCALE : -1e9f;
      float mx = fmaxf(fmaxf(s0,s1), fmaxf(s2,s3));
      if (qtl == 0) rmax0 = fmaxf(rmax0, mx); else rmax1 = fmaxf(rmax1, mx);
      const int lrow = qtl*16 + c;                 // local row 0..31
      uint2 pk;
      pk.x = pkh2(s0, s1);
      pk.y = pkh2(s2, s3);
      *(uint2*)(lds + lrow*4096 + ((kb*2) ^ ((lrow & 7) << 4))) = pk;
    }
  }
  // in-wave reduce over lane groups (cols identical for same c)
  rmax0 = fmaxf(rmax0, __shfl_xor(rmax0, 16));
  rmax0 = fmaxf(rmax0, __shfl_xor(rmax0, 32));
  rmax1 = fmaxf(rmax1, __shfl_xor(rmax1, 16));
  rmax1 = fmaxf(rmax1, __shfl_xor(rmax1, 32));
  if (l < 16)      mbuf[w*32 + l] = rmax0;        // qtile0: rows 0..15
  else if (l < 32) mbuf[w*32 + l] = rmax1;        // qtile1: rows 16..31
  __syncthreads();
  if (tid < 32) {
    float m = mbuf[tid];
#pragma unroll 1
    for (int ww = 1; ww < 16; ++ww) m = fmaxf(m, mbuf[ww*32 + tid]);
    maxr[tid] = m;
  }
  __syncthreads();

  // ---- Phase B+C: per-row softmax; wave w owns rows 2w, 2w+1
#pragma unroll
  for (int rr = 0; rr < 2; ++rr) {
    const int row  = 2*w + rr;
    const float mrow = maxr[row];
    const int swz  = (row & 7) << 4;
    uint4 hv[4];
    float sum = 0.f;
#pragma unroll
    for (int it = 0; it < 4; ++it) {
      const int raw = l*16 + it*1024;              // semantic byte (= 2k)
      hv[it] = *(const uint4*)(lds + row*4096 + (raw ^ swz));
      const unsigned int* wp = (const unsigned int*)&hv[it];
#pragma unroll
      for (int u = 0; u < 4; ++u) {
        unsigned int wd = wp[u];
        sum += __expf(h2f((unsigned short)(wd & 0xFFFFu)) - mrow)
             + __expf(h2f((unsigned short)(wd >> 16))     - mrow);
      }
    }
#pragma unroll
    for (int off = 32; off >= 1; off >>= 1) sum += __shfl_xor(sum, off);
    const float inv = 1.0f / sum;
    float* prow = pout + ((size_t)b*LL + q0 + row)*LL;
#pragma unroll
    for (int it = 0; it < 4; ++it) {
      const int raw = l*16 + it*1024;
      const int kbase = raw >> 1;
      const unsigned int* wp = (const unsigned int*)&hv[it];
      float pv[8];
#pragma unroll
      for (int u = 0; u < 4; ++u) {
        unsigned int wd = wp[u];
        pv[2*u]   = __expf(h2f((unsigned short)(wd & 0xFFFFu)) - mrow) * inv;
        pv[2*u+1] = __expf(h2f((unsigned short)(wd >> 16))     - mrow) * inv;
      }
      float4 o0 = {pv[0],pv[1],pv[2],pv[3]};
      float4 o1 = {pv[4],pv[5],pv[6],pv[7]};
      *(float4*)(prow + kbase)     = o0;
      *(float4*)(prow + kbase + 4) = o1;
      uint4 pb;
      pb.x = (unsigned int)f2bf(pv[0]) | ((unsigned int)f2bf(pv[1]) << 16);
      pb.y = (unsigned int)f2bf(pv[2]) | ((unsigned int)f2bf(pv[3]) << 16);
      pb.z = (unsigned int)f2bf(pv[4]) | ((unsigned int)f2bf(pv[5]) << 16);
      pb.w = (unsigned int)f2bf(pv[6]) | ((unsigned int)f2bf(pv[7]) << 16);
      *(uint4*)(lds + row*4096 + (raw ^ swz)) = pb;   // P as bf16, in place
    }
  }
  __syncthreads();

  // ---- Phase D: context = P (LDS bf16, A-op) * V (Vt global bf16, B-op)
  const int qt = w >> 3, dt = w & 7;
  const int prow = qt*16 + c;
  const int pswz = (prow & 7) << 4;
  const char* pbase = lds + prow*4096;
  const unsigned short* vtb = Vt + ((size_t)b*DD + dt*16 + c)*LL;
  f32x4 acc0 = {0.f,0.f,0.f,0.f}, acc1 = {0.f,0.f,0.f,0.f};
#pragma unroll 4
  for (int ks = 0; ks < 64; ks += 2) {
    const int k0 = ks*32 + g*8;
    const int k1 = k0 + 32;
    short8 a0 = *(const short8*)(pbase + ((k0*2) ^ pswz));
    short8 b0 = *(const short8*)(vtb + k0);
    short8 a1 = *(const short8*)(pbase + ((k1*2) ^ pswz));
    short8 b1 = *(const short8*)(vtb + k1);
    acc0 = MFMA(a0, b0, acc0);
    acc1 = MFMA(a1, b1, acc1);
  }
#pragma unroll
  for (int r = 0; r < 4; ++r) {
    const int q = q0 + qt*16 + g*4 + r;
    ctxout[((size_t)b*LL + q)*DD + dt*16 + c] = acc0[r] + acc1[r];
  }
}

// ---------- fallback (ws too small): simple correct version ----------
__global__ __launch_bounds__(256) void attn_naive(
    const float* __restrict__ Q, const float* __restrict__ K,
    const float* __restrict__ V, const int* __restrict__ M,
    float* __restrict__ ctx, float* __restrict__ pout)
{
  const int b = blockIdx.x >> 11;
  const int q = blockIdx.x & (LL-1);
  __shared__ float s[LL];
  __shared__ float red[256];
  const int tid = threadIdx.x;
  const float* qp = Q + ((size_t)b*LL + q)*DD;
  for (int kk = tid; kk < LL; kk += 256) {
    const float* kp = K + ((size_t)b*LL + kk)*DD;
    float a = 0.f;
    for (int d = 0; d < DD; ++d) a += qp[d]*kp[d];
    s[kk] = M[((size_t)b*LL + q)*LL + kk] ? a*SCALE : -1e9f;
  }
  __syncthreads();
  float mx = -3e38f;
  for (int kk = tid; kk < LL; kk += 256) mx = fmaxf(mx, s[kk]);
  red[tid] = mx; __syncthreads();
  for (int o = 128; o >= 1; o >>= 1) {
    if (tid < o) red[tid] = fmaxf(red[tid], red[tid+o]);
    __syncthreads();
  }
  const float mrow = red[0]; __syncthreads();
  float sm = 0.f;
  for (int kk = tid; kk < LL; kk += 256) { float e = __expf(s[kk]-mrow); s[kk] = e; sm += e; }
  red[tid] = sm; __syncthreads();
  for (int o = 128; o >= 1; o >>= 1) {
    if (tid < o) red[tid] += red[tid+o];
    __syncthreads();
  }
  const float inv = 1.0f / red[0]; __syncthreads();
  float* prow = pout + ((size_t)b*LL + q)*LL;
  for (int kk = tid; kk < LL; kk += 256) { s[kk] *= inv; prow[kk] = s[kk]; }
  __syncthreads();
  if (tid < DD) {
    float a = 0.f;
    for (int kk = 0; kk < LL; ++kk) a += s[kk]*V[((size_t)b*LL + kk)*DD + tid];
    ctx[((size_t)b*LL + q)*DD + tid] = a;
  }
}

extern "C" void kernel_launch(void* const* d_in, const int* in_sizes, int n_in,
                              void* d_out, int out_size, void* d_ws, size_t ws_size,
                              hipStream_t stream) {
  (void)in_sizes; (void)n_in; (void)out_size;
  const float* Q = (const float*)d_in[0];
  const float* K = (const float*)d_in[1];
  const float* V = (const float*)d_in[2];
  const int*   M = (const int*)d_in[3];
  float* ctx  = (float*)d_out;
  float* pout = ctx + (size_t)BB*LL*DD;
  const size_t WS_NEED = (size_t)BB*LL*DD*2*3;     // Kh + Kl + Vt (bf16)
  if (ws_size >= WS_NEED) {
    unsigned short* Kh = (unsigned short*)d_ws;
    unsigned short* Kl = Kh + (size_t)BB*LL*DD;
    unsigned short* Vt = Kl + (size_t)BB*LL*DD;
    hipFuncSetAttribute(reinterpret_cast<const void*>(attn_main),
                        hipFuncAttributeMaxDynamicSharedMemorySize, LDS_BYTES);
    prep_k <<<2048, 256, 0, stream>>>(K, Kh, Kl);
    prep_vt<<<4096, 256, 0, stream>>>(V, Vt);
    attn_main<<<1024, 1024, LDS_BYTES, stream>>>(Q, M, Kh, Kl, Vt, ctx, pout);
  } else {
    attn_naive<<<BB*LL, 256, 0, stream>>>(Q, K, V, M, ctx, pout);
  }
}